// Round 6
// baseline (180.483 us; speedup 1.0000x reference)
//
#include <hip/hip_runtime.h>

// LIF neuron scan over time (dim 0).
// x: (T=8, 16, 64, 56, 56) f32.  Per spatial element, sequential over t:
//   mem   = (mem_old - spike_prev) * 0.25 + x[t]
//   spike = round(clip(mem, 0, 4))      // round-half-to-even, like jnp.round
// out[t] = spike.
//
// R1: load->use serial chain, VGPR=32, MLP=1, 30% HBM, latency-bound.
// R4: source-level load clustering was re-sunk by the scheduler (VGPR=28!),
//     neutral. Fix: asm volatile memory barrier after the load phase —
//     loads cannot legally sink past a potential memory-writing asm, so all
//     8 global_load_dwordx4 must issue first. MLP 1-2 -> 8.
// R5: broker timeout, no data. Identical resubmit.

constexpr int   LIF_T     = 8;
constexpr float LIF_DECAY = 0.25f;

__global__ __launch_bounds__(256) void
lif_kernel(const float4* __restrict__ x, float4* __restrict__ out, int n4)
{
    // Match the numpy/JAX fp32 reference exactly: separate sub/mul/add
    // roundings (no FMA contraction), so round() never flips at .5 edges.
    #pragma clang fp contract(off)

    const int i = blockIdx.x * blockDim.x + threadIdx.x;
    if (i >= n4) return;

    // Phase 1: issue all 8 loads (independent addresses -> 8 outstanding).
    float4 v[LIF_T];
    #pragma unroll
    for (int t = 0; t < LIF_T; ++t)
        v[t] = x[t * n4 + i];

    // Scheduler fence: loads may not sink below this (asm may write memory).
    asm volatile("" ::: "memory");

    // Phase 2: serial LIF scan in registers; overwrite v[t] with spikes.
    float mx = 0.f, my = 0.f, mz = 0.f, mw = 0.f;   // mem
    float sx = 0.f, sy = 0.f, sz = 0.f, sw = 0.f;   // spike
    #pragma unroll
    for (int t = 0; t < LIF_T; ++t) {
        mx = (mx - sx) * LIF_DECAY + v[t].x;
        my = (my - sy) * LIF_DECAY + v[t].y;
        mz = (mz - sz) * LIF_DECAY + v[t].z;
        mw = (mw - sw) * LIF_DECAY + v[t].w;

        sx = rintf(fminf(fmaxf(mx, 0.f), 4.f));
        sy = rintf(fminf(fmaxf(my, 0.f), 4.f));
        sz = rintf(fminf(fmaxf(mz, 0.f), 4.f));
        sw = rintf(fminf(fmaxf(mw, 0.f), 4.f));

        v[t] = make_float4(sx, sy, sz, sw);
    }

    // Phase 3: store all 8.
    #pragma unroll
    for (int t = 0; t < LIF_T; ++t)
        out[t * n4 + i] = v[t];
}

// Scalar fallback for any tail elements not divisible by 4 (not expected for
// this shape, but harmless).
__global__ void
lif_kernel_tail(const float* __restrict__ x, float* __restrict__ out,
                int n_per_t, int start)
{
    #pragma clang fp contract(off)
    const int i = start + blockIdx.x * blockDim.x + threadIdx.x;
    if (i >= n_per_t) return;

    float mem = 0.f, spike = 0.f;
    #pragma unroll
    for (int t = 0; t < LIF_T; ++t) {
        mem   = (mem - spike) * LIF_DECAY + x[t * n_per_t + i];
        spike = rintf(fminf(fmaxf(mem, 0.f), 4.f));
        out[t * n_per_t + i] = spike;
    }
}

extern "C" void kernel_launch(void* const* d_in, const int* in_sizes, int n_in,
                              void* d_out, int out_size, void* d_ws, size_t ws_size,
                              hipStream_t stream)
{
    const float* x   = (const float*)d_in[0];
    float*       out = (float*)d_out;

    const int n_total = in_sizes[0];          // T * N
    const int n_per_t = n_total / LIF_T;      // spatial elements per timestep
    const int n4      = n_per_t / 4;          // float4 chunks per timestep

    if (n4 > 0) {
        const int block = 256;
        const int grid  = (n4 + block - 1) / block;   // 3136 blocks for this shape
        lif_kernel<<<grid, block, 0, stream>>>(
            (const float4*)x, (float4*)out, n4);
    }

    const int tail_start = n4 * 4;
    const int tail_n     = n_per_t - tail_start;
    if (tail_n > 0) {
        const int block = 64;
        const int grid  = (tail_n + block - 1) / block;
        lif_kernel_tail<<<grid, block, 0, stream>>>(x, out, n_per_t, tail_start);
    }
}